// Round 10
// baseline (645.782 us; speedup 1.0000x reference)
//
#include <hip/hip_runtime.h>
#include <hip/hip_bf16.h>
#include <cmath>

// ---- problem constants ----
constexpr int cB  = 2;
constexpr int cS  = 1024;
constexpr int cNH = 32;
constexpr int cHD = 128;
constexpr int cHID = 4096;
constexpr int cM  = cB * cS;        // 2048 rows

typedef unsigned short u16;
typedef __bf16 bf16x8 __attribute__((ext_vector_type(8)));
typedef float  f32x4  __attribute__((ext_vector_type(4)));

__device__ __forceinline__ u16 f2b(float f) { return __builtin_bit_cast(u16, (__bf16)f); }

// ---------------- f32 -> bf16, 8 elems/thread ----------------
__global__ void cvt_bf16(const float* __restrict__ in, u16* __restrict__ out, int n8) {
  int i = blockIdx.x * blockDim.x + threadIdx.x;
  if (i >= n8) return;
  const float4* in4 = (const float4*)in;
  float4 a = in4[2 * i], b = in4[2 * i + 1];
  union { u16 u[8]; uint4 v; } r;
  r.u[0] = f2b(a.x); r.u[1] = f2b(a.y); r.u[2] = f2b(a.z); r.u[3] = f2b(a.w);
  r.u[4] = f2b(b.x); r.u[5] = f2b(b.y); r.u[6] = f2b(b.z); r.u[7] = f2b(b.w);
  ((uint4*)out)[i] = r.v;
}

// ---------------- 3 weights f32 -> bf16 in one launch ----------------
__global__ void cvt3(const float* __restrict__ A0, const float* __restrict__ A1,
                     const float* __restrict__ A2,
                     u16* __restrict__ O0, u16* __restrict__ O1, u16* __restrict__ O2) {
  int idx = blockIdx.x * blockDim.x + threadIdx.x;   // < 3 * 2^21
  int sel = idx >> 21, t = idx & ((1 << 21) - 1);
  const float* in = (sel == 0) ? A0 : (sel == 1 ? A1 : A2);
  u16* out = (sel == 0) ? O0 : (sel == 1 ? O1 : O2);
  const float4* in4 = (const float4*)in;
  float4 a = in4[2 * t], b = in4[2 * t + 1];
  union { u16 u[8]; uint4 v; } rv;
  rv.u[0] = f2b(a.x); rv.u[1] = f2b(a.y); rv.u[2] = f2b(a.z); rv.u[3] = f2b(a.w);
  rv.u[4] = f2b(b.x); rv.u[5] = f2b(b.y); rv.u[6] = f2b(b.z); rv.u[7] = f2b(b.w);
  ((uint4*)out)[t] = rv.v;
}

// ---------------- RoPE cos/sin table: [B*S][64] ----------------
__global__ void rope_table_k(const int* __restrict__ pos,
                             float* __restrict__ cosT, float* __restrict__ sinT) {
  int idx = blockIdx.x * blockDim.x + threadIdx.x;   // < B*S*64
  int i = idx & 63, bs = idx >> 6;
  float p = (float)pos[bs];
  float freq = exp2f(-(float)i * (13.287712379549449f / 64.0f));
  float a = p * freq;
  float s, c;
  sincosf(a, &s, &c);
  cosT[idx] = c; sinT[idx] = s;
}

// ---------------- RoPE in-place on Q and K (bf16), interleaved pairs ------
__global__ void rope_apply(u16* __restrict__ Q, u16* __restrict__ Kb,
                           const float* __restrict__ cosT, const float* __restrict__ sinT) {
  int idx = blockIdx.x * blockDim.x + threadIdx.x;
  const int nPer = cB * cS * cNH * (cHD / 8);        // 1,048,576
  u16* P = (idx < nPer) ? Q : Kb;
  int t = (idx < nPer) ? idx : idx - nPer;
  int d8 = t & 15;
  int h  = (t >> 4) & 31;
  int bs = t >> 9;
  size_t base = ((size_t)bs * cNH + h) * cHD + d8 * 8;
  uint4 v = *reinterpret_cast<uint4*>(P + base);
  u16* u = reinterpret_cast<u16*>(&v);
  int pb = bs * 64 + d8 * 4;
  float4 cs = *reinterpret_cast<const float4*>(cosT + pb);
  float4 sn = *reinterpret_cast<const float4*>(sinT + pb);
  float co[4] = {cs.x, cs.y, cs.z, cs.w};
  float si[4] = {sn.x, sn.y, sn.z, sn.w};
#pragma unroll
  for (int p = 0; p < 4; ++p) {
    float e = (float)__builtin_bit_cast(__bf16, u[2 * p]);
    float o = (float)__builtin_bit_cast(__bf16, u[2 * p + 1]);
    float e2 = e * co[p] - o * si[p];
    float o2 = o * co[p] + e * si[p];
    u[2 * p]     = f2b(e2);
    u[2 * p + 1] = f2b(o2);
  }
  *reinterpret_cast<uint4*>(P + base) = v;
}

// ---------------- V [B,S,NH,HD] -> Vt [B*NH, HD, S] ----------------
__global__ void transpose_v(const u16* __restrict__ V, u16* __restrict__ Vt) {
  __shared__ u16 tile[32][33];
  int bh = blockIdx.z;
  int b = bh >> 5, h = bh & 31;
  int s0 = blockIdx.x * 32, d0 = blockIdx.y * 32;
  int tx = threadIdx.x & 31, ty0 = threadIdx.x >> 5;
#pragma unroll
  for (int i = 0; i < 4; ++i) {
    int r = ty0 + i * 8;
    tile[r][tx] = V[((size_t)(b * cS + s0 + r) * cNH + h) * cHD + d0 + tx];
  }
  __syncthreads();
#pragma unroll
  for (int i = 0; i < 4; ++i) {
    int r = ty0 + i * 8;
    Vt[((size_t)bh * cHD + d0 + r) * cS + s0 + tx] = tile[tx][r];
  }
}

// ---------------- pipelined GEMM (round-6/8-proven) ----------------
// 128x256 tile, BK=64, 512 thr/8 waves, depth-2 prefetch, 3 LDS buffers,
// ONE barrier per K-tile, counted vmcnt(6), T2 swizzle both sides
// (bank conflicts = 0), setprio-wrapped MFMA clusters.
template <int MODE>   // 0: bf16 out, 1: f32 out
__global__ __launch_bounds__(512, 2)
void gemm8(const u16* __restrict__ A,
           const u16* __restrict__ W0, const u16* __restrict__ W1,
           const u16* __restrict__ W2,
           const float* __restrict__ b0, const float* __restrict__ b1,
           const float* __restrict__ b2,
           void* o0, void* o1, void* o2) {
  __shared__ __align__(16) u16 sA[3][128 * 64];
  __shared__ __align__(16) u16 sB[3][256 * 64];
  const int tid = threadIdx.x;
  const int wid = tid >> 6, lane = tid & 63;
  const int c = lane & 15, g = lane >> 4;
  const int wm = wid >> 2, wn = wid & 3;
  const int m0 = blockIdx.x * 128;
  const int gn0 = blockIdx.y * 256;
  const int sel = gn0 >> 12;
  const int n0 = gn0 & 4095;
  const u16* Bw = (sel == 0) ? W0 : (sel == 1 ? W1 : W2);

  f32x4 acc[4][4] = {};
  const int nkt = cHID / 64;

#define STAGE_A(kt, dst)                                                       \
  {                                                                            \
    _Pragma("unroll") for (int l = 0; l < 2; ++l) {                            \
      int chunk = (l * 8 + wid) * 64 + lane;                                   \
      int row = chunk >> 3, kc = (chunk & 7) ^ (row & 7);                      \
      __builtin_amdgcn_global_load_lds(                                        \
          (const void*)(A + (size_t)(m0 + row) * cHID + (kt) * 64 + kc * 8),   \
          (void*)(&sA[dst][(l * 8 + wid) * 512]), 16, 0, 0);                   \
    }                                                                          \
  }
#define STAGE_B(kt, dst)                                                       \
  {                                                                            \
    _Pragma("unroll") for (int l = 0; l < 4; ++l) {                            \
      int chunk = (l * 8 + wid) * 64 + lane;                                   \
      int row = chunk >> 3, kc = (chunk & 7) ^ (row & 7);                      \
      __builtin_amdgcn_global_load_lds(                                        \
          (const void*)(Bw + (size_t)(n0 + row) * cHID + (kt) * 64 + kc * 8),  \
          (void*)(&sB[dst][(l * 8 + wid) * 512]), 16, 0, 0);                   \
    }                                                                          \
  }

  STAGE_A(0, 0); STAGE_B(0, 0);
  STAGE_A(1, 1); STAGE_B(1, 1);
  asm volatile("s_waitcnt vmcnt(6)" ::: "memory");
  __builtin_amdgcn_sched_barrier(0);
  __builtin_amdgcn_s_barrier();
  asm volatile("" ::: "memory");
  __builtin_amdgcn_sched_barrier(0);

  for (int kt = 0; kt < nkt; ++kt) {
    const int bufR = kt % 3;
    const int bufW = (kt + 2) % 3;
    const bool doStage = (kt + 2) < nkt;

    bf16x8 af[4], bw[4];
#pragma unroll
    for (int mf = 0; mf < 4; ++mf) {
      int ra = wm * 64 + mf * 16 + c;
      af[mf] = *reinterpret_cast<const bf16x8*>(
          &sA[bufR][ra * 64 + ((g ^ (ra & 7)) * 8)]);
    }
#pragma unroll
    for (int nf = 0; nf < 4; ++nf) {
      int rb = wn * 64 + nf * 16 + c;
      bw[nf] = *reinterpret_cast<const bf16x8*>(
          &sB[bufR][rb * 64 + ((g ^ (rb & 7)) * 8)]);
    }
    if (doStage) STAGE_A(kt + 2, bufW);
    __builtin_amdgcn_s_setprio(1);
#pragma unroll
    for (int mf = 0; mf < 4; ++mf)
#pragma unroll
      for (int nf = 0; nf < 4; ++nf)
        acc[mf][nf] = __builtin_amdgcn_mfma_f32_16x16x32_bf16(af[mf], bw[nf], acc[mf][nf], 0, 0, 0);
    __builtin_amdgcn_s_setprio(0);

#pragma unroll
    for (int mf = 0; mf < 4; ++mf) {
      int ra = wm * 64 + mf * 16 + c;
      af[mf] = *reinterpret_cast<const bf16x8*>(
          &sA[bufR][ra * 64 + (((4 + g) ^ (ra & 7)) * 8)]);
    }
#pragma unroll
    for (int nf = 0; nf < 4; ++nf) {
      int rb = wn * 64 + nf * 16 + c;
      bw[nf] = *reinterpret_cast<const bf16x8*>(
          &sB[bufR][rb * 64 + (((4 + g) ^ (rb & 7)) * 8)]);
    }
    if (doStage) STAGE_B(kt + 2, bufW);
    __builtin_amdgcn_s_setprio(1);
#pragma unroll
    for (int mf = 0; mf < 4; ++mf)
#pragma unroll
      for (int nf = 0; nf < 4; ++nf)
        acc[mf][nf] = __builtin_amdgcn_mfma_f32_16x16x32_bf16(af[mf], bw[nf], acc[mf][nf], 0, 0, 0);
    __builtin_amdgcn_s_setprio(0);

    if (doStage) {
      asm volatile("s_waitcnt vmcnt(6)" ::: "memory");
    } else {
      asm volatile("s_waitcnt vmcnt(0)" ::: "memory");
    }
    __builtin_amdgcn_sched_barrier(0);
    __builtin_amdgcn_s_barrier();
    asm volatile("" ::: "memory");
    __builtin_amdgcn_sched_barrier(0);
  }
#undef STAGE_A
#undef STAGE_B

  const float* bp = (sel == 0) ? b0 : (sel == 1 ? b1 : b2);
  void* op = (sel == 0) ? o0 : (sel == 1 ? o1 : o2);
#pragma unroll
  for (int nf = 0; nf < 4; ++nf) {
    int col = n0 + wn * 64 + nf * 16 + c;
    float bv = bp[col];
#pragma unroll
    for (int mf = 0; mf < 4; ++mf) {
      int row = m0 + wm * 64 + mf * 16 + g * 4;
#pragma unroll
      for (int r = 0; r < 4; ++r) {
        float v = acc[mf][nf][r] + bv;
        if (MODE == 0)
          ((u16*)op)[(size_t)(row + r) * cHID + col] = f2b(v);
        else
          ((float*)op)[(size_t)(row + r) * cHID + col] = v;
      }
    }
  }
}

// ---------------- flash attention (causal), 1 q-tile/block, 4 waves -------
// r10: unpaired grid (16 q-tiles x 64 heads = 1024 blocks), HEAVY-FIRST
// (qt = 15 - blockIdx.x) so long blocks dispatch first and light ones
// backfill. 40 KB LDS + <=128 VGPR -> 4 blocks/CU resident (2x r8 TLP).
// V direct from global (L2-resident, r8-proven), 4 fragments in flight.
__global__ __launch_bounds__(256, 4)
void attn_kernel(const u16* __restrict__ Q, const u16* __restrict__ Kb,
                 const u16* __restrict__ Vt, u16* __restrict__ O) {
  __shared__ __align__(16) char sK[2][16384];  // [64 k][128 d] swizzled
  __shared__ __align__(16) char sP[8192];      // per-wave [16 q][64 k] swizzled
  const int tid = threadIdx.x, w = tid >> 6, lane = tid & 63;
  const int c = lane & 15, g = lane >> 4;
  const int bh = blockIdx.y;
  const int b = bh >> 5, h = bh & 31;
  const int NT = cS / 64;                       // 16
  const int qt = NT - 1 - blockIdx.x;           // heavy first
  const int q0 = qt * 64;
  const float kSc = 0.12751744f;                // log2(e)/sqrt(128)
  const u16* Vg = Vt + (size_t)bh * (cHD * cS); // [128 d][1024 s]

  bf16x8 qf[4];
  {
    size_t qrow = ((size_t)(b * cS + q0 + w * 16 + c) * cNH + h) * cHD;
#pragma unroll
    for (int df = 0; df < 4; ++df)
      qf[df] = *reinterpret_cast<const bf16x8*>(Q + qrow + df * 32 + g * 8);
  }

  f32x4 o[8] = {};
  float mx[4] = {-1e30f, -1e30f, -1e30f, -1e30f};
  float ls[4] = {0.f, 0.f, 0.f, 0.f};

  uint4 kv[4];
#define LOADT(t)                                                               \
  {                                                                            \
    _Pragma("unroll") for (int i = 0; i < 4; ++i) {                            \
      int cidx = i * 256 + tid;                                                \
      int row = cidx >> 4, ch = cidx & 15;                                     \
      kv[i] = *reinterpret_cast<const uint4*>(                                 \
          Kb + ((size_t)(b * cS + (t) * 64 + row) * cNH + h) * cHD + ch * 8);  \
    }                                                                          \
  }
#define WRITET(buf)                                                            \
  {                                                                            \
    _Pragma("unroll") for (int i = 0; i < 4; ++i) {                            \
      int cidx = i * 256 + tid;                                                \
      int row = cidx >> 4, ch = cidx & 15;                                     \
      *reinterpret_cast<uint4*>(sK[buf] + row * 256 + ((ch ^ (row & 7)) * 16)) = kv[i]; \
    }                                                                          \
  }

  LOADT(0);
  WRITET(0);
  int cur = 0;

  for (int t = 0; t <= qt; ++t) {
    __syncthreads();                 // K tile t visible
    if (t < qt) LOADT(t + 1);        // issue-early (T14)

    // ---- QK^T: scores [16 q][64 k] in 4 col-frags
    f32x4 sc[4] = {};
#pragma unroll
    for (int df = 0; df < 4; ++df) {
      bf16x8 kb[4];
#pragma unroll
      for (int cf = 0; cf < 4; ++cf) {
        int kr = cf * 16 + c;
        kb[cf] = *reinterpret_cast<const bf16x8*>(sK[cur] + kr * 256 + (((df * 4 + g) ^ (kr & 7)) * 16));
      }
#pragma unroll
      for (int cf = 0; cf < 4; ++cf)
        sc[cf] = __builtin_amdgcn_mfma_f32_16x16x32_bf16(qf[df], kb[cf], sc[cf], 0, 0, 0);
    }

    // ---- causal mask on diagonal tile
    if (t == qt) {
#pragma unroll
      for (int cf = 0; cf < 4; ++cf) {
        int kg = t * 64 + cf * 16 + c;
#pragma unroll
        for (int r = 0; r < 4; ++r) {
          int qg = q0 + w * 16 + g * 4 + r;
          if (kg > qg) sc[cf][r] = -1e30f;
        }
      }
    }

    // ---- online softmax (wave-parallel over 16-lane column groups)
    float alpha[4];
#pragma unroll
    for (int r = 0; r < 4; ++r) {
      float v = fmaxf(fmaxf(sc[0][r], sc[1][r]), fmaxf(sc[2][r], sc[3][r]));
      v = fmaxf(v, __shfl_xor(v, 1));
      v = fmaxf(v, __shfl_xor(v, 2));
      v = fmaxf(v, __shfl_xor(v, 4));
      v = fmaxf(v, __shfl_xor(v, 8));
      float mn = fmaxf(mx[r], v);
      alpha[r] = exp2f((mx[r] - mn) * kSc);
      mx[r] = mn;
    }
    float rs[4] = {0.f, 0.f, 0.f, 0.f};
#pragma unroll
    for (int cf = 0; cf < 4; ++cf)
#pragma unroll
      for (int r = 0; r < 4; ++r) {
        float p = exp2f((sc[cf][r] - mx[r]) * kSc);
        sc[cf][r] = p;
        rs[r] += p;
      }
#pragma unroll
    for (int r = 0; r < 4; ++r) {
      float v = rs[r];
      v += __shfl_xor(v, 1); v += __shfl_xor(v, 2);
      v += __shfl_xor(v, 4); v += __shfl_xor(v, 8);
      ls[r] = ls[r] * alpha[r] + v;
    }
#pragma unroll
    for (int nf = 0; nf < 8; ++nf)
#pragma unroll
      for (int r = 0; r < 4; ++r)
        o[nf][r] *= alpha[r];

    // ---- P (C layout) -> per-wave LDS (bf16, swizzled) for A-operand
    char* myP = sP + w * 2048;
#pragma unroll
    for (int cf = 0; cf < 4; ++cf) {
      int kcol = cf * 16 + c;
      int chunk = kcol >> 3, within = kcol & 7;
#pragma unroll
      for (int r = 0; r < 4; ++r) {
        int qr = g * 4 + r;
        *reinterpret_cast<u16*>(myP + qr * 128 + ((chunk ^ (qr & 7)) * 16) + within * 2) =
            f2b(sc[cf][r]);
      }
    }
    bf16x8 pa[2];
#pragma unroll
    for (int kf = 0; kf < 2; ++kf)
      pa[kf] = *reinterpret_cast<const bf16x8*>(myP + c * 128 + (((kf * 4 + g) ^ (c & 7)) * 16));

    // ---- PV: V fragments direct from global (L2-hot), 4 in flight
#pragma unroll
    for (int kf = 0; kf < 2; ++kf) {
#pragma unroll
      for (int h2 = 0; h2 < 2; ++h2) {
        bf16x8 vb[4];
#pragma unroll
        for (int j = 0; j < 4; ++j)
          vb[j] = *reinterpret_cast<const bf16x8*>(
              Vg + (size_t)((h2 * 4 + j) * 16 + c) * cS + t * 64 + (kf * 4 + g) * 8);
#pragma unroll
        for (int j = 0; j < 4; ++j)
          o[h2 * 4 + j] = __builtin_amdgcn_mfma_f32_16x16x32_bf16(pa[kf], vb[j], o[h2 * 4 + j], 0, 0, 0);
      }
    }

    if (t < qt) { WRITET(cur ^ 1); cur ^= 1; }
  }

  // ---- finalize: O /= l, stage in sK[0] for coalesced store
  __syncthreads();
#pragma unroll
  for (int nf = 0; nf < 8; ++nf) {
#pragma unroll
    for (int r = 0; r < 4; ++r) {
      float v = o[nf][r] / ls[r];
      int qr = w * 16 + g * 4 + r;
      *reinterpret_cast<u16*>(sK[0] + qr * 256 + (nf * 16 + c) * 2) = f2b(v);
    }
  }
  __syncthreads();
#pragma unroll
  for (int i = 0; i < 4; ++i) {
    int cidx = i * 256 + tid;
    int row = cidx >> 4, ch = cidx & 15;
    uint4 v = *reinterpret_cast<const uint4*>(sK[0] + row * 256 + ch * 16);
    *reinterpret_cast<uint4*>(O + ((size_t)(b * cS + q0 + row) * cNH + h) * cHD + ch * 8) = v;
  }
#undef LOADT
#undef WRITET
}

// ---------------- host ----------------
extern "C" void kernel_launch(void* const* d_in, const int* in_sizes, int n_in,
                              void* d_out, int out_size, void* d_ws, size_t ws_size,
                              hipStream_t stream) {
  const float* x  = (const float*)d_in[0];
  const float* Wq = (const float*)d_in[1];
  const float* bq = (const float*)d_in[2];
  const float* Wk = (const float*)d_in[3];
  const float* bk = (const float*)d_in[4];
  const float* Wv = (const float*)d_in[5];
  const float* bv = (const float*)d_in[6];
  const float* Wo = (const float*)d_in[7];
  const float* bo = (const float*)d_in[8];
  const int*  pos = (const int*)d_in[9];
  float* out = (float*)d_out;

  char* ws = (char*)d_ws;
  const size_t MB = 1u << 20;
  const int W8 = (cHID * cHID) / 8;     // 2,097,152 = 1<<21
  const int X8 = (cM * cHID) / 8;       // 1,048,576
  const int R8 = cB * cS * cNH * (cHD / 8);

  if (ws_size >= 168 * MB) {
    // -------- fused path (168 MiB) --------
    u16* xb  = (u16*)(ws);                 // 0-16
    u16* Qb  = (u16*)(ws + 16 * MB);       // 16-32
    u16* Kb  = (u16*)(ws + 32 * MB);       // 32-48
    u16* Vb  = (u16*)(ws + 48 * MB);       // 48-64
    float* cosT = (float*)(ws + 64 * MB);  // 64-65
    float* sinT = cosT + cB * cS * 64;
    u16* WbQ = (u16*)(ws + 72 * MB);       // 72-104
    u16* WbK = (u16*)(ws + 104 * MB);      // 104-136
    u16* WbV = (u16*)(ws + 136 * MB);      // 136-168
    u16* Vt  = WbQ;                        // weights dead after QKV GEMM
    u16* Ab  = WbK;
    u16* WbO = WbV;

    // weights first; x LAST so it is L3-hottest when the QKV GEMM starts
    cvt3<<<(3 * W8) / 256, 256, 0, stream>>>(Wq, Wk, Wv, WbQ, WbK, WbV);
    rope_table_k<<<(cB * cS * 64) / 256, 256, 0, stream>>>(pos, cosT, sinT);
    cvt_bf16<<<X8 / 256, 256, 0, stream>>>(x, xb, X8);

    gemm8<0><<<dim3(16, 48), 512, 0, stream>>>(
        xb, WbQ, WbK, WbV, bq, bk, bv, Qb, Kb, Vb);

    rope_apply<<<(2 * R8) / 256, 256, 0, stream>>>(Qb, Kb, cosT, sinT);
    transpose_v<<<dim3(cS / 32, cHD / 32, cB * cNH), 256, 0, stream>>>(Vb, Vt);
    attn_kernel<<<dim3(cS / 64, cB * cNH), 256, 0, stream>>>(Qb, Kb, Vt, Ab);

    cvt_bf16<<<W8 / 256, 256, 0, stream>>>(Wo, WbO, W8);
    gemm8<1><<<dim3(16, 16), 512, 0, stream>>>(
        Ab, WbO, WbO, WbO, bo, bo, bo, out, out, out);
  } else {
    // -------- fallback serial path (97 MiB) --------
    u16* xb = (u16*)(ws);                 // 0-16, later Vt
    u16* Wb = (u16*)(ws + 16 * MB);       // 16-48
    u16* Qb = (u16*)(ws + 48 * MB);       // 48-64
    u16* Kb = (u16*)(ws + 64 * MB);       // 64-80
    u16* Vb = (u16*)(ws + 80 * MB);       // 80-96, later attn out
    u16* Vt = xb;
    u16* Ab = Vb;
    float* cosT = (float*)(ws + 96 * MB);
    float* sinT = cosT + cB * cS * 64;

    cvt_bf16<<<X8 / 256, 256, 0, stream>>>(x, xb, X8);
    cvt_bf16<<<W8 / 256, 256, 0, stream>>>(Wq, Wb, W8);
    gemm8<0><<<dim3(16, 16), 512, 0, stream>>>(
        xb, Wb, Wb, Wb, bq, bq, bq, Qb, Qb, Qb);
    cvt_bf16<<<W8 / 256, 256, 0, stream>>>(Wk, Wb, W8);
    gemm8<0><<<dim3(16, 16), 512, 0, stream>>>(
        xb, Wb, Wb, Wb, bk, bk, bk, Kb, Kb, Kb);
    cvt_bf16<<<W8 / 256, 256, 0, stream>>>(Wv, Wb, W8);
    gemm8<0><<<dim3(16, 16), 512, 0, stream>>>(
        xb, Wb, Wb, Wb, bv, bv, bv, Vb, Vb, Vb);

    rope_table_k<<<(cB * cS * 64) / 256, 256, 0, stream>>>(pos, cosT, sinT);
    rope_apply<<<(2 * R8) / 256, 256, 0, stream>>>(Qb, Kb, cosT, sinT);
    transpose_v<<<dim3(cS / 32, cHD / 32, cB * cNH), 256, 0, stream>>>(Vb, Vt);
    attn_kernel<<<dim3(cS / 64, cB * cNH), 256, 0, stream>>>(Qb, Kb, Vt, Ab);

    cvt_bf16<<<W8 / 256, 256, 0, stream>>>(Wo, Wb, W8);
    gemm8<1><<<dim3(16, 16), 512, 0, stream>>>(
        Ab, Wb, Wb, Wb, bo, bo, bo, out, out, out);
  }
}

// Round 11
// 445.362 us; speedup vs baseline: 1.4500x; 1.4500x over previous
//
#include <hip/hip_runtime.h>
#include <hip/hip_bf16.h>
#include <cmath>

// ---- problem constants ----
constexpr int cB  = 2;
constexpr int cS  = 1024;
constexpr int cNH = 32;
constexpr int cHD = 128;
constexpr int cHID = 4096;
constexpr int cM  = cB * cS;        // 2048 rows

typedef unsigned short u16;
typedef __bf16 bf16x8 __attribute__((ext_vector_type(8)));
typedef float  f32x4  __attribute__((ext_vector_type(4)));

__device__ __forceinline__ u16 f2b(float f) { return __builtin_bit_cast(u16, (__bf16)f); }

// ---------------- f32 -> bf16, 8 elems/thread ----------------
__global__ void cvt_bf16(const float* __restrict__ in, u16* __restrict__ out, int n8) {
  int i = blockIdx.x * blockDim.x + threadIdx.x;
  if (i >= n8) return;
  const float4* in4 = (const float4*)in;
  float4 a = in4[2 * i], b = in4[2 * i + 1];
  union { u16 u[8]; uint4 v; } r;
  r.u[0] = f2b(a.x); r.u[1] = f2b(a.y); r.u[2] = f2b(a.z); r.u[3] = f2b(a.w);
  r.u[4] = f2b(b.x); r.u[5] = f2b(b.y); r.u[6] = f2b(b.z); r.u[7] = f2b(b.w);
  ((uint4*)out)[i] = r.v;
}

// ---------------- 3 weights f32 -> bf16 in one launch ----------------
__global__ void cvt3(const float* __restrict__ A0, const float* __restrict__ A1,
                     const float* __restrict__ A2,
                     u16* __restrict__ O0, u16* __restrict__ O1, u16* __restrict__ O2) {
  int idx = blockIdx.x * blockDim.x + threadIdx.x;   // < 3 * 2^21
  int sel = idx >> 21, t = idx & ((1 << 21) - 1);
  const float* in = (sel == 0) ? A0 : (sel == 1 ? A1 : A2);
  u16* out = (sel == 0) ? O0 : (sel == 1 ? O1 : O2);
  const float4* in4 = (const float4*)in;
  float4 a = in4[2 * t], b = in4[2 * t + 1];
  union { u16 u[8]; uint4 v; } rv;
  rv.u[0] = f2b(a.x); rv.u[1] = f2b(a.y); rv.u[2] = f2b(a.z); rv.u[3] = f2b(a.w);
  rv.u[4] = f2b(b.x); rv.u[5] = f2b(b.y); rv.u[6] = f2b(b.z); rv.u[7] = f2b(b.w);
  ((uint4*)out)[t] = rv.v;
}

// ---------------- RoPE cos/sin table: [B*S][64] ----------------
__global__ void rope_table_k(const int* __restrict__ pos,
                             float* __restrict__ cosT, float* __restrict__ sinT) {
  int idx = blockIdx.x * blockDim.x + threadIdx.x;   // < B*S*64
  int i = idx & 63, bs = idx >> 6;
  float p = (float)pos[bs];
  float freq = exp2f(-(float)i * (13.287712379549449f / 64.0f));
  float a = p * freq;
  float s, c;
  sincosf(a, &s, &c);
  cosT[idx] = c; sinT[idx] = s;
}

// ---------------- RoPE in-place (FALLBACK PATH ONLY) ----------------
__global__ void rope_apply(u16* __restrict__ Q, u16* __restrict__ Kb,
                           const float* __restrict__ cosT, const float* __restrict__ sinT) {
  int idx = blockIdx.x * blockDim.x + threadIdx.x;
  const int nPer = cB * cS * cNH * (cHD / 8);        // 1,048,576
  u16* P = (idx < nPer) ? Q : Kb;
  int t = (idx < nPer) ? idx : idx - nPer;
  int d8 = t & 15;
  int h  = (t >> 4) & 31;
  int bs = t >> 9;
  size_t base = ((size_t)bs * cNH + h) * cHD + d8 * 8;
  uint4 v = *reinterpret_cast<uint4*>(P + base);
  u16* u = reinterpret_cast<u16*>(&v);
  int pb = bs * 64 + d8 * 4;
  float4 cs = *reinterpret_cast<const float4*>(cosT + pb);
  float4 sn = *reinterpret_cast<const float4*>(sinT + pb);
  float co[4] = {cs.x, cs.y, cs.z, cs.w};
  float si[4] = {sn.x, sn.y, sn.z, sn.w};
#pragma unroll
  for (int p = 0; p < 4; ++p) {
    float e = (float)__builtin_bit_cast(__bf16, u[2 * p]);
    float o = (float)__builtin_bit_cast(__bf16, u[2 * p + 1]);
    float e2 = e * co[p] - o * si[p];
    float o2 = o * co[p] + e * si[p];
    u[2 * p]     = f2b(e2);
    u[2 * p + 1] = f2b(o2);
  }
  *reinterpret_cast<uint4*>(P + base) = v;
}

// ---------------- V transpose (FALLBACK PATH ONLY) ----------------
__global__ void transpose_v(const u16* __restrict__ V, u16* __restrict__ Vt) {
  __shared__ u16 tile[32][33];
  int bh = blockIdx.z;
  int b = bh >> 5, h = bh & 31;
  int s0 = blockIdx.x * 32, d0 = blockIdx.y * 32;
  int tx = threadIdx.x & 31, ty0 = threadIdx.x >> 5;
#pragma unroll
  for (int i = 0; i < 4; ++i) {
    int r = ty0 + i * 8;
    tile[r][tx] = V[((size_t)(b * cS + s0 + r) * cNH + h) * cHD + d0 + tx];
  }
  __syncthreads();
#pragma unroll
  for (int i = 0; i < 4; ++i) {
    int r = ty0 + i * 8;
    Vt[((size_t)bh * cHD + d0 + r) * cS + s0 + tx] = tile[tx][r];
  }
}

// ---------------- pipelined GEMM (round-6/8-proven schedule) --------------
// 128x256 tile, BK=64, 512 thr/8 waves, depth-2 prefetch, 3 LDS buffers,
// ONE barrier per K-tile, counted vmcnt(6), T2 swizzle both sides
// (bank conflicts = 0), setprio-wrapped MFMA clusters.
// MODE 0: QKV fused epilogue — sel<2: RoPE applied in-register (pair value
//         via __shfl_xor(v,1), cos/sin from table) then bf16 store;
//         sel==2: V stored TRANSPOSED into Vt[bh][d][s] (o2) as ushort4.
// MODE 1: f32 out + bias (O-proj). MODE 3: plain bf16 + bias (fallback).
template <int MODE>
__global__ __launch_bounds__(512, 2)
void gemm8(const u16* __restrict__ A,
           const u16* __restrict__ W0, const u16* __restrict__ W1,
           const u16* __restrict__ W2,
           const float* __restrict__ b0, const float* __restrict__ b1,
           const float* __restrict__ b2,
           void* o0, void* o1, void* o2,
           const float* __restrict__ cosT, const float* __restrict__ sinT) {
  __shared__ __align__(16) u16 sA[3][128 * 64];
  __shared__ __align__(16) u16 sB[3][256 * 64];
  const int tid = threadIdx.x;
  const int wid = tid >> 6, lane = tid & 63;
  const int c = lane & 15, g = lane >> 4;
  const int wm = wid >> 2, wn = wid & 3;
  const int m0 = blockIdx.x * 128;
  const int gn0 = blockIdx.y * 256;
  const int sel = gn0 >> 12;
  const int n0 = gn0 & 4095;
  const u16* Bw = (sel == 0) ? W0 : (sel == 1 ? W1 : W2);

  f32x4 acc[4][4] = {};
  const int nkt = cHID / 64;

#define STAGE_A(kt, dst)                                                       \
  {                                                                            \
    _Pragma("unroll") for (int l = 0; l < 2; ++l) {                            \
      int chunk = (l * 8 + wid) * 64 + lane;                                   \
      int row = chunk >> 3, kc = (chunk & 7) ^ (row & 7);                      \
      __builtin_amdgcn_global_load_lds(                                        \
          (const void*)(A + (size_t)(m0 + row) * cHID + (kt) * 64 + kc * 8),   \
          (void*)(&sA[dst][(l * 8 + wid) * 512]), 16, 0, 0);                   \
    }                                                                          \
  }
#define STAGE_B(kt, dst)                                                       \
  {                                                                            \
    _Pragma("unroll") for (int l = 0; l < 4; ++l) {                            \
      int chunk = (l * 8 + wid) * 64 + lane;                                   \
      int row = chunk >> 3, kc = (chunk & 7) ^ (row & 7);                      \
      __builtin_amdgcn_global_load_lds(                                        \
          (const void*)(Bw + (size_t)(n0 + row) * cHID + (kt) * 64 + kc * 8),  \
          (void*)(&sB[dst][(l * 8 + wid) * 512]), 16, 0, 0);                   \
    }                                                                          \
  }

  STAGE_A(0, 0); STAGE_B(0, 0);
  STAGE_A(1, 1); STAGE_B(1, 1);
  asm volatile("s_waitcnt vmcnt(6)" ::: "memory");
  __builtin_amdgcn_sched_barrier(0);
  __builtin_amdgcn_s_barrier();
  asm volatile("" ::: "memory");
  __builtin_amdgcn_sched_barrier(0);

  for (int kt = 0; kt < nkt; ++kt) {
    const int bufR = kt % 3;
    const int bufW = (kt + 2) % 3;
    const bool doStage = (kt + 2) < nkt;

    bf16x8 af[4], bw[4];
#pragma unroll
    for (int mf = 0; mf < 4; ++mf) {
      int ra = wm * 64 + mf * 16 + c;
      af[mf] = *reinterpret_cast<const bf16x8*>(
          &sA[bufR][ra * 64 + ((g ^ (ra & 7)) * 8)]);
    }
#pragma unroll
    for (int nf = 0; nf < 4; ++nf) {
      int rb = wn * 64 + nf * 16 + c;
      bw[nf] = *reinterpret_cast<const bf16x8*>(
          &sB[bufR][rb * 64 + ((g ^ (rb & 7)) * 8)]);
    }
    if (doStage) STAGE_A(kt + 2, bufW);
    __builtin_amdgcn_s_setprio(1);
#pragma unroll
    for (int mf = 0; mf < 4; ++mf)
#pragma unroll
      for (int nf = 0; nf < 4; ++nf)
        acc[mf][nf] = __builtin_amdgcn_mfma_f32_16x16x32_bf16(af[mf], bw[nf], acc[mf][nf], 0, 0, 0);
    __builtin_amdgcn_s_setprio(0);

#pragma unroll
    for (int mf = 0; mf < 4; ++mf) {
      int ra = wm * 64 + mf * 16 + c;
      af[mf] = *reinterpret_cast<const bf16x8*>(
          &sA[bufR][ra * 64 + (((4 + g) ^ (ra & 7)) * 8)]);
    }
#pragma unroll
    for (int nf = 0; nf < 4; ++nf) {
      int rb = wn * 64 + nf * 16 + c;
      bw[nf] = *reinterpret_cast<const bf16x8*>(
          &sB[bufR][rb * 64 + (((4 + g) ^ (rb & 7)) * 8)]);
    }
    if (doStage) STAGE_B(kt + 2, bufW);
    __builtin_amdgcn_s_setprio(1);
#pragma unroll
    for (int mf = 0; mf < 4; ++mf)
#pragma unroll
      for (int nf = 0; nf < 4; ++nf)
        acc[mf][nf] = __builtin_amdgcn_mfma_f32_16x16x32_bf16(af[mf], bw[nf], acc[mf][nf], 0, 0, 0);
    __builtin_amdgcn_s_setprio(0);

    if (doStage) {
      asm volatile("s_waitcnt vmcnt(6)" ::: "memory");
    } else {
      asm volatile("s_waitcnt vmcnt(0)" ::: "memory");
    }
    __builtin_amdgcn_sched_barrier(0);
    __builtin_amdgcn_s_barrier();
    asm volatile("" ::: "memory");
    __builtin_amdgcn_sched_barrier(0);
  }
#undef STAGE_A
#undef STAGE_B

  const float* bp = (sel == 0) ? b0 : (sel == 1 ? b1 : b2);
  void* op = (sel == 0) ? o0 : (sel == 1 ? o1 : o2);

  if (MODE == 0 && sel < 2) {
    // ---- Q/K epilogue: bias + RoPE (pair via shfl_xor lane^1) + bf16 store
#pragma unroll
    for (int nf = 0; nf < 4; ++nf) {
      int col = n0 + wn * 64 + nf * 16 + c;
      float bv = bp[col];
      int ih = (((wn & 1) * 64) + nf * 16 + c) >> 1;   // pair index in head
#pragma unroll
      for (int mf = 0; mf < 4; ++mf) {
        int row0 = m0 + wm * 64 + mf * 16 + g * 4;
#pragma unroll
        for (int r = 0; r < 4; ++r) {
          int row = row0 + r;
          float v = acc[mf][nf][r] + bv;
          float vp = __shfl_xor(v, 1);                 // partner col^1 value
          float cs = cosT[row * 64 + ih];
          float sn = sinT[row * 64 + ih];
          v = (c & 1) ? fmaf(vp, sn, v * cs)           // odd:  o*c + e*s
                      : fmaf(-vp, sn, v * cs);         // even: e*c - o*s
          ((u16*)op)[(size_t)row * cHID + col] = f2b(v);
        }
      }
    }
  } else if (MODE == 0) {
    // ---- V epilogue: bias + TRANSPOSED store into Vt[bh][d][s] (op == o2)
    u16* vt = (u16*)op;
#pragma unroll
    for (int nf = 0; nf < 4; ++nf) {
      int col = n0 + wn * 64 + nf * 16 + c;
      float bv = bp[col];
      int hh = col >> 7, dd = col & 127;
#pragma unroll
      for (int mf = 0; mf < 4; ++mf) {
        int row0 = m0 + wm * 64 + mf * 16 + g * 4;
        int bb = row0 >> 10, sl = row0 & 1023;
        ushort4 pk;
        pk.x = f2b(acc[mf][nf][0] + bv);
        pk.y = f2b(acc[mf][nf][1] + bv);
        pk.z = f2b(acc[mf][nf][2] + bv);
        pk.w = f2b(acc[mf][nf][3] + bv);
        *reinterpret_cast<ushort4*>(
            vt + ((size_t)(bb * cNH + hh) * cHD + dd) * cS + sl) = pk;
      }
    }
  } else {
#pragma unroll
    for (int nf = 0; nf < 4; ++nf) {
      int col = n0 + wn * 64 + nf * 16 + c;
      float bv = bp[col];
#pragma unroll
      for (int mf = 0; mf < 4; ++mf) {
        int row = m0 + wm * 64 + mf * 16 + g * 4;
#pragma unroll
        for (int r = 0; r < 4; ++r) {
          float v = acc[mf][nf][r] + bv;
          if (MODE == 1)
            ((float*)op)[(size_t)(row + r) * cHID + col] = v;
          else
            ((u16*)op)[(size_t)(row + r) * cHID + col] = f2b(v);
        }
      }
    }
  }
}

// ---------------- flash attention (r8-proven, verbatim) -------------------
// Paired q-tiles serial in block, 256 thr / 4 waves, launch_bounds(256,2)
// (VGPR cap 256 — NO spill; r10's (256,4) cap caused 210 MB scratch traffic).
// K double-buffered in LDS (swizzled); V direct from global (L2-resident).
__global__ __launch_bounds__(256, 2)
void attn_kernel(const u16* __restrict__ Q, const u16* __restrict__ Kb,
                 const u16* __restrict__ Vt, u16* __restrict__ O) {
  __shared__ __align__(16) char sK[2][16384];  // [64 k][128 d] swizzled
  __shared__ __align__(16) char sP[8192];      // per-wave [16 q][64 k] swizzled
  const int tid = threadIdx.x, w = tid >> 6, lane = tid & 63;
  const int c = lane & 15, g = lane >> 4;
  const int bh = blockIdx.y;
  const int b = bh >> 5, h = bh & 31;
  const int NT = cS / 64;                       // 16
  const int qtA = blockIdx.x, qtB = NT - 1 - blockIdx.x;
  const float kSc = 0.12751744f;                // log2(e)/sqrt(128)
  const u16* Vg = Vt + (size_t)bh * (cHD * cS); // [128 d][1024 s]

  bf16x8 qf[2][4];
#pragma unroll
  for (int s = 0; s < 2; ++s) {
    int q0s = (s ? qtA : qtB) * 64;
    size_t qrow = ((size_t)(b * cS + q0s + w * 16 + c) * cNH + h) * cHD;
#pragma unroll
    for (int df = 0; df < 4; ++df)
      qf[s][df] = *reinterpret_cast<const bf16x8*>(Q + qrow + df * 32 + g * 8);
  }

  f32x4 o[2][8] = {};
  float mx[2][4], ls[2][4];
#pragma unroll
  for (int s = 0; s < 2; ++s)
#pragma unroll
    for (int r = 0; r < 4; ++r) { mx[s][r] = -1e30f; ls[s][r] = 0.f; }

  uint4 kv[4];
#define LOADT(t)                                                               \
  {                                                                            \
    _Pragma("unroll") for (int i = 0; i < 4; ++i) {                            \
      int cidx = i * 256 + tid;                                                \
      int row = cidx >> 4, ch = cidx & 15;                                     \
      kv[i] = *reinterpret_cast<const uint4*>(                                 \
          Kb + ((size_t)(b * cS + (t) * 64 + row) * cNH + h) * cHD + ch * 8);  \
    }                                                                          \
  }
#define WRITET(buf)                                                            \
  {                                                                            \
    _Pragma("unroll") for (int i = 0; i < 4; ++i) {                            \
      int cidx = i * 256 + tid;                                                \
      int row = cidx >> 4, ch = cidx & 15;                                     \
      *reinterpret_cast<uint4*>(sK[buf] + row * 256 + ((ch ^ (row & 7)) * 16)) = kv[i]; \
    }                                                                          \
  }

  LOADT(0);
  WRITET(0);
  int cur = 0;

  for (int t = 0; t <= qtB; ++t) {
    __syncthreads();
    if (t < qtB) LOADT(t + 1);

#pragma unroll
    for (int s = 0; s < 2; ++s) {
      const int qt_s = s ? qtA : qtB;
      if (t > qt_s) continue;
      const int q0_s = qt_s * 64;

      f32x4 sc[4] = {};
#pragma unroll
      for (int df = 0; df < 4; ++df) {
        bf16x8 kb[4];
#pragma unroll
        for (int cf = 0; cf < 4; ++cf) {
          int kr = cf * 16 + c;
          kb[cf] = *reinterpret_cast<const bf16x8*>(sK[cur] + kr * 256 + (((df * 4 + g) ^ (kr & 7)) * 16));
        }
#pragma unroll
        for (int cf = 0; cf < 4; ++cf)
          sc[cf] = __builtin_amdgcn_mfma_f32_16x16x32_bf16(qf[s][df], kb[cf], sc[cf], 0, 0, 0);
      }

      if (t == qt_s) {
#pragma unroll
        for (int cf = 0; cf < 4; ++cf) {
          int kg = t * 64 + cf * 16 + c;
#pragma unroll
          for (int r = 0; r < 4; ++r) {
            int qg = q0_s + w * 16 + g * 4 + r;
            if (kg > qg) sc[cf][r] = -1e30f;
          }
        }
      }

      float alpha[4];
#pragma unroll
      for (int r = 0; r < 4; ++r) {
        float v = fmaxf(fmaxf(sc[0][r], sc[1][r]), fmaxf(sc[2][r], sc[3][r]));
        v = fmaxf(v, __shfl_xor(v, 1));
        v = fmaxf(v, __shfl_xor(v, 2));
        v = fmaxf(v, __shfl_xor(v, 4));
        v = fmaxf(v, __shfl_xor(v, 8));
        float mn = fmaxf(mx[s][r], v);
        alpha[r] = exp2f((mx[s][r] - mn) * kSc);
        mx[s][r] = mn;
      }
      float rs[4] = {0.f, 0.f, 0.f, 0.f};
#pragma unroll
      for (int cf = 0; cf < 4; ++cf)
#pragma unroll
        for (int r = 0; r < 4; ++r) {
          float p = exp2f((sc[cf][r] - mx[s][r]) * kSc);
          sc[cf][r] = p;
          rs[r] += p;
        }
#pragma unroll
      for (int r = 0; r < 4; ++r) {
        float v = rs[r];
        v += __shfl_xor(v, 1); v += __shfl_xor(v, 2);
        v += __shfl_xor(v, 4); v += __shfl_xor(v, 8);
        ls[s][r] = ls[s][r] * alpha[r] + v;
      }
#pragma unroll
      for (int nf = 0; nf < 8; ++nf)
#pragma unroll
        for (int r = 0; r < 4; ++r)
          o[s][nf][r] *= alpha[r];

      char* myP = sP + w * 2048;
#pragma unroll
      for (int cf = 0; cf < 4; ++cf) {
        int kcol = cf * 16 + c;
        int chunk = kcol >> 3, within = kcol & 7;
#pragma unroll
        for (int r = 0; r < 4; ++r) {
          int qr = g * 4 + r;
          *reinterpret_cast<u16*>(myP + qr * 128 + ((chunk ^ (qr & 7)) * 16) + within * 2) =
              f2b(sc[cf][r]);
        }
      }
      bf16x8 pa[2];
#pragma unroll
      for (int kf = 0; kf < 2; ++kf)
        pa[kf] = *reinterpret_cast<const bf16x8*>(myP + c * 128 + (((kf * 4 + g) ^ (c & 7)) * 16));

#pragma unroll
      for (int kf = 0; kf < 2; ++kf) {
        bf16x8 vb[8];
#pragma unroll
        for (int nf = 0; nf < 8; ++nf)
          vb[nf] = *reinterpret_cast<const bf16x8*>(
              Vg + (size_t)(nf * 16 + c) * cS + t * 64 + (kf * 4 + g) * 8);
#pragma unroll
        for (int nf = 0; nf < 8; ++nf)
          o[s][nf] = __builtin_amdgcn_mfma_f32_16x16x32_bf16(pa[kf], vb[nf], o[s][nf], 0, 0, 0);
      }
    }

    if (t < qtB) { WRITET(cur ^ 1); cur ^= 1; }
  }

  __syncthreads();
#pragma unroll
  for (int s = 0; s < 2; ++s) {
#pragma unroll
    for (int nf = 0; nf < 8; ++nf) {
#pragma unroll
      for (int r = 0; r < 4; ++r) {
        float v = o[s][nf][r] / ls[s][r];
        int qr = w * 16 + g * 4 + r;
        *reinterpret_cast<u16*>(sK[s] + qr * 256 + (nf * 16 + c) * 2) = f2b(v);
      }
    }
  }
  __syncthreads();
#pragma unroll
  for (int s = 0; s < 2; ++s) {
    int q0_s = (s ? qtA : qtB) * 64;
#pragma unroll
    for (int i = 0; i < 4; ++i) {
      int cidx = i * 256 + tid;
      int row = cidx >> 4, ch = cidx & 15;
      uint4 v = *reinterpret_cast<const uint4*>(sK[s] + row * 256 + ch * 16);
      *reinterpret_cast<uint4*>(O + ((size_t)(b * cS + q0_s + row) * cNH + h) * cHD + ch * 8) = v;
    }
  }
#undef LOADT
#undef WRITET
}

// ---------------- host ----------------
extern "C" void kernel_launch(void* const* d_in, const int* in_sizes, int n_in,
                              void* d_out, int out_size, void* d_ws, size_t ws_size,
                              hipStream_t stream) {
  const float* x  = (const float*)d_in[0];
  const float* Wq = (const float*)d_in[1];
  const float* bq = (const float*)d_in[2];
  const float* Wk = (const float*)d_in[3];
  const float* bk = (const float*)d_in[4];
  const float* Wv = (const float*)d_in[5];
  const float* bv = (const float*)d_in[6];
  const float* Wo = (const float*)d_in[7];
  const float* bo = (const float*)d_in[8];
  const int*  pos = (const int*)d_in[9];
  float* out = (float*)d_out;

  char* ws = (char*)d_ws;
  const size_t MB = 1u << 20;
  const int W8 = (cHID * cHID) / 8;     // 2,097,152 = 1<<21
  const int X8 = (cM * cHID) / 8;       // 1,048,576
  const int R8 = cB * cS * cNH * (cHD / 8);

  if (ws_size >= 168 * MB) {
    // -------- fused path (168 MiB) --------
    u16* xb  = (u16*)(ws);                 // 0-16
    u16* Qb  = (u16*)(ws + 16 * MB);       // 16-32  (RoPE'd by GEMM epilogue)
    u16* Kb  = (u16*)(ws + 32 * MB);       // 32-48  (RoPE'd by GEMM epilogue)
    u16* Vt  = (u16*)(ws + 48 * MB);       // 48-64  (transposed by GEMM epilogue)
    float* cosT = (float*)(ws + 64 * MB);  // 64-64.5
    float* sinT = cosT + cB * cS * 64;     // 64.5-65
    u16* WbQ = (u16*)(ws + 72 * MB);       // 72-104
    u16* WbK = (u16*)(ws + 104 * MB);      // 104-136
    u16* WbV = (u16*)(ws + 136 * MB);      // 136-168
    u16* Ab  = WbQ;                        // attn out: WbQ dead after QKV GEMM
    u16* WbO = WbK;                        // Wo bf16:  WbK dead after QKV GEMM

    // weights first; x LAST so it is L3-hottest when the QKV GEMM starts
    cvt3<<<(3 * W8) / 256, 256, 0, stream>>>(Wq, Wk, Wv, WbQ, WbK, WbV);
    rope_table_k<<<(cB * cS * 64) / 256, 256, 0, stream>>>(pos, cosT, sinT);
    cvt_bf16<<<X8 / 256, 256, 0, stream>>>(x, xb, X8);

    // QKV GEMM with fused RoPE (Q,K) and fused V-transpose (-> Vt)
    gemm8<0><<<dim3(16, 48), 512, 0, stream>>>(
        xb, WbQ, WbK, WbV, bq, bk, bv, Qb, Kb, Vt, cosT, sinT);

    attn_kernel<<<dim3(cS / 128, cB * cNH), 256, 0, stream>>>(Qb, Kb, Vt, Ab);

    cvt_bf16<<<W8 / 256, 256, 0, stream>>>(Wo, WbO, W8);
    gemm8<1><<<dim3(16, 16), 512, 0, stream>>>(
        Ab, WbO, WbO, WbO, bo, bo, bo, out, out, out, nullptr, nullptr);
  } else {
    // -------- fallback serial path (97 MiB, separate rope/transpose) ------
    u16* xb = (u16*)(ws);                 // 0-16, later Vt
    u16* Wb = (u16*)(ws + 16 * MB);       // 16-48
    u16* Qb = (u16*)(ws + 48 * MB);       // 48-64
    u16* Kb = (u16*)(ws + 64 * MB);       // 64-80
    u16* Vb = (u16*)(ws + 80 * MB);       // 80-96, later attn out
    u16* Vt = xb;
    u16* Ab = Vb;
    float* cosT = (float*)(ws + 96 * MB);
    float* sinT = cosT + cB * cS * 64;

    cvt_bf16<<<X8 / 256, 256, 0, stream>>>(x, xb, X8);
    cvt_bf16<<<W8 / 256, 256, 0, stream>>>(Wq, Wb, W8);
    gemm8<3><<<dim3(16, 16), 512, 0, stream>>>(
        xb, Wb, Wb, Wb, bq, bq, bq, Qb, Qb, Qb, nullptr, nullptr);
    cvt_bf16<<<W8 / 256, 256, 0, stream>>>(Wk, Wb, W8);
    gemm8<3><<<dim3(16, 16), 512, 0, stream>>>(
        xb, Wb, Wb, Wb, bk, bk, bk, Kb, Kb, Kb, nullptr, nullptr);
    cvt_bf16<<<W8 / 256, 256, 0, stream>>>(Wv, Wb, W8);
    gemm8<3><<<dim3(16, 16), 512, 0, stream>>>(
        xb, Wb, Wb, Wb, bv, bv, bv, Vb, Vb, Vb, nullptr, nullptr);

    rope_table_k<<<(cB * cS * 64) / 256, 256, 0, stream>>>(pos, cosT, sinT);
    rope_apply<<<(2 * R8) / 256, 256, 0, stream>>>(Qb, Kb, cosT, sinT);
    transpose_v<<<dim3(cS / 32, cHD / 32, cB * cNH), 256, 0, stream>>>(Vb, Vt);
    attn_kernel<<<dim3(cS / 128, cB * cNH), 256, 0, stream>>>(Qb, Kb, Vt, Ab);

    cvt_bf16<<<W8 / 256, 256, 0, stream>>>(Wo, Wb, W8);
    gemm8<1><<<dim3(16, 16), 512, 0, stream>>>(
        Ab, Wb, Wb, Wb, bo, bo, bo, out, out, out, nullptr, nullptr);
  }
}